// Round 1
// 58.886 us; speedup vs baseline: 1.0068x; 1.0068x over previous
//
#include <hip/hip_runtime.h>

#define MASK_PENALTY (-10000)

typedef int v4i __attribute__((ext_vector_type(4)));

// One block per batch row, 1024 threads (16 waves), one int4 per thread.
// Changes vs previous version (59.29 us):
//  - X passed from host (derived from out_size) -> no device scalar load of x_steps.
//  - LDS zero-init and hist writeback vectorized to b128 (threads 0..255 only;
//    waves 4..15 fall through to the barrier / exit immediately).
//  - Non-temporal stores for both outputs: they are never re-read on device,
//    so don't dirty L2 -> smaller end-of-dispatch release flush.
//  - Global int4 load + output_length load issued before any LDS work so HBM
//    latency overlaps the init phase (kept from previous version).
__global__ __launch_bounds__(1024) void DurationCalculator_87677462380947_kernel(
    const int* __restrict__ duration,       // [B, Y] int32
    const int* __restrict__ output_length,  // [B] int32
    int* __restrict__ out_wa,               // [B, Y] int32
    int* __restrict__ out_hist,             // [B, X] int32
    int Y, int X)
{
    const int b = blockIdx.x;
    const int v = threadIdx.x;              // 0..1023

    // Issue all global loads up front (before any barrier).
    const v4i* __restrict__ drow = (const v4i*)(duration + (size_t)b * Y);
    v4i d = drow[v];                        // global_load_dwordx4 issues here
    const int len = output_length[b];       // uniform -> s_load

    __shared__ int hist[1024];
    v4i* __restrict__ h4 = (v4i*)hist;
    const int X4 = X >> 2;                  // 256 for this problem
    const v4i zero = {0, 0, 0, 0};
    for (int i = v; i < X4; i += blockDim.x) h4[i] = zero;   // ds_write_b128
    __syncthreads();

    const int y0 = v << 2;
    v4i w;
    w.x = d.x + ((y0 + 0) < len ? 0 : MASK_PENALTY);
    w.y = d.y + ((y0 + 1) < len ? 0 : MASK_PENALTY);
    w.z = d.z + ((y0 + 2) < len ? 0 : MASK_PENALTY);
    w.w = d.w + ((y0 + 3) < len ? 0 : MASK_PENALTY);

    // Store first so the VMEM write drains while the LDS atomics run.
    // NT: out_wa is never re-read on device -> don't pollute/dirty L2.
    __builtin_nontemporal_store(w, (v4i*)(out_wa + (size_t)b * Y) + v);

    // (unsigned)w < X  <=>  0 <= w < X  (masked values are negative)
    if ((unsigned)w.x < (unsigned)X) atomicAdd(&hist[w.x], 1);
    if ((unsigned)w.y < (unsigned)X) atomicAdd(&hist[w.y], 1);
    if ((unsigned)w.z < (unsigned)X) atomicAdd(&hist[w.z], 1);
    if ((unsigned)w.w < (unsigned)X) atomicAdd(&hist[w.w], 1);
    __syncthreads();

    int* __restrict__ orow = out_hist + (size_t)b * X;
    for (int i = v; i < X4; i += blockDim.x) {
        v4i h = h4[i];                       // ds_read_b128
        __builtin_nontemporal_store(h, (v4i*)orow + i);
    }
}

extern "C" void kernel_launch(void* const* d_in, const int* in_sizes, int n_in,
                              void* d_out, int out_size, void* d_ws, size_t ws_size,
                              hipStream_t stream) {
    const int* duration      = (const int*)d_in[0];  // B*Y
    const int* output_length = (const int*)d_in[1];  // B
    // d_in[2] (x_steps scalar) intentionally unused: X derived host-side below.

    const int B = in_sizes[1];
    const int Y = in_sizes[0] / B;                   // 4096
    const int X = (out_size - in_sizes[0]) / B;      // 1024

    int* out_wa   = (int*)d_out;                     // first B*Y ints
    int* out_hist = (int*)d_out + (size_t)B * Y;     // then B*X ints
    (void)n_in; (void)d_ws; (void)ws_size;

    DurationCalculator_87677462380947_kernel<<<B, 1024, 0, stream>>>(
        duration, output_length, out_wa, out_hist, Y, X);
}